// Round 5
// baseline (504.513 us; speedup 1.0000x reference)
//
#include <hip/hip_runtime.h>

typedef unsigned short u16;
typedef __bf16 bf16x8 __attribute__((ext_vector_type(8)));
typedef unsigned short u16x8 __attribute__((ext_vector_type(8)));
typedef float f32x4 __attribute__((ext_vector_type(4)));

#define M_ROWS 8232
#define SEQ 1029
#define NPREF 5
#define DIMN 1024
#define NH 16
#define HD 64

// raw barrier for attn: LDS-only wait, no vmem drain
#define BAR_LGKM asm volatile("s_waitcnt lgkmcnt(0)\ns_barrier" ::: "memory")

__device__ __forceinline__ u16 f2bf(float f) {
  unsigned u = __float_as_uint(f);
  u += 0x7fffu + ((u >> 16) & 1u);
  return (u16)(u >> 16);
}

__device__ __forceinline__ unsigned pk2bf(float lo, float hi) {
  unsigned ul = __float_as_uint(lo);
  unsigned uh = __float_as_uint(hi);
  ul += 0x7fffu + ((ul >> 16) & 1u);
  uh += 0x7fffu + ((uh >> 16) & 1u);
  return __builtin_amdgcn_perm(uh, ul, 0x07060302u);
}

// ---------------- x (fp32) -> bf16 ----------------
__global__ __launch_bounds__(256) void k_cvt_x(const float* __restrict__ x, u16* __restrict__ xb) {
  size_t i = ((size_t)blockIdx.x * 256 + threadIdx.x) * 4;
  float4 v = *reinterpret_cast<const float4*>(x + i);
  ushort4 o;
  o.x = f2bf(v.x); o.y = f2bf(v.y); o.z = f2bf(v.z); o.w = f2bf(v.w);
  *reinterpret_cast<ushort4*>(xb + i) = o;
}

// ---------------- W (fp32 [K][N]) -> WT (bf16 [N][K]) ----------------
__global__ __launch_bounds__(256) void k_wt(const float* __restrict__ W0, const float* __restrict__ W1,
                                            const float* __restrict__ W2, const float* __restrict__ W3,
                                            u16* __restrict__ T0, u16* __restrict__ T1,
                                            u16* __restrict__ T2, u16* __restrict__ T3) {
  const float* W; u16* T;
  switch (blockIdx.z) {
    case 0: W = W0; T = T0; break;
    case 1: W = W1; T = T1; break;
    case 2: W = W2; T = T2; break;
    default: W = W3; T = T3; break;
  }
  __shared__ float tile[32][33];
  int tx = threadIdx.x & 31, ty = threadIdx.x >> 5;
  int k0 = blockIdx.x * 32, n0 = blockIdx.y * 32;
#pragma unroll
  for (int j = 0; j < 4; ++j)
    tile[ty + j * 8][tx] = W[(size_t)(k0 + ty + j * 8) * DIMN + n0 + tx];
  __syncthreads();
#pragma unroll
  for (int j = 0; j < 4; ++j)
    T[(size_t)(n0 + ty + j * 8) * DIMN + k0 + tx] = f2bf(tile[tx][ty + j * 8]);
}

// ---------------- fused QKV projection GEMM, LDS-free register pipeline ----------------
// grid 1560 = mode(3, slowest) x mt(65) x nt(8, fastest).
// Both A and B fragments loaded global->VGPR in MFMA layout; no LDS, no barriers.
__global__ __launch_bounds__(256) void k_qkv(
    const u16* __restrict__ Xb,
    const u16* __restrict__ WqT, const u16* __restrict__ WkT, const u16* __restrict__ WvT,
    const float* __restrict__ bq, const float* __restrict__ bv,
    const float* __restrict__ rc, const float* __restrict__ rs,
    u16* __restrict__ Qg, u16* __restrict__ Kg, u16* __restrict__ Vg)
{
  int bid = blockIdx.x;
  int nt = bid & 7;
  int tmp = bid >> 3;         // 0..194
  int mt = tmp % 65;
  int mode = tmp / 65;
  const u16* WT = (mode == 0) ? WqT : (mode == 1) ? WkT : WvT;
  u16* dst = (mode == 0) ? Qg : (mode == 1) ? Kg : Vg;
  int m0 = mt * 128, n0 = nt * 128;

  int t = threadIdx.x, lane = t & 63, wv = t >> 6;
  int fr = lane & 15, quad = lane >> 4;
  int wm = (wv >> 1) * 64, wn = (wv & 1) * 64;

  // per-lane fragment base pointers (computed once; loop offsets are immediates)
  const u16* ap[4];
  const u16* bp[4];
#pragma unroll
  for (int i = 0; i < 4; ++i) {
    int arow = m0 + wm + i * 16 + fr; if (arow >= M_ROWS) arow = M_ROWS - 1;
    ap[i] = Xb + (size_t)arow * DIMN + quad * 8;
    int brow = n0 + wn + i * 16 + fr;
    bp[i] = WT + (size_t)brow * DIMN + quad * 8;
  }

  f32x4 zero4 = {0.f, 0.f, 0.f, 0.f};
  f32x4 acc[4][4];
#pragma unroll
  for (int i = 0; i < 4; ++i)
#pragma unroll
    for (int j = 0; j < 4; ++j) acc[i][j] = zero4;

  bf16x8 ac[4], bc[4], an[4], bn[4];
#pragma unroll
  for (int i = 0; i < 4; ++i) {
    ac[i] = *reinterpret_cast<const bf16x8*>(ap[i]);
    bc[i] = *reinterpret_cast<const bf16x8*>(bp[i]);
  }

#pragma unroll 2
  for (int k0 = 0; k0 < DIMN; k0 += 32) {
    if (k0 < DIMN - 32) {
#pragma unroll
      for (int i = 0; i < 4; ++i) {
        an[i] = *reinterpret_cast<const bf16x8*>(ap[i] + k0 + 32);
        bn[i] = *reinterpret_cast<const bf16x8*>(bp[i] + k0 + 32);
      }
    }
#pragma unroll
    for (int i = 0; i < 4; ++i)
#pragma unroll
      for (int j = 0; j < 4; ++j)
        acc[i][j] = __builtin_amdgcn_mfma_f32_16x16x32_bf16(ac[i], bc[j], acc[i][j], 0, 0, 0);
#pragma unroll
    for (int i = 0; i < 4; ++i) { ac[i] = an[i]; bc[i] = bn[i]; }
  }

  int h = (n0 + wn) >> 6;
#pragma unroll
  for (int i = 0; i < 4; ++i) {
    int rowbase = m0 + wm + i * 16 + quad * 4;
#pragma unroll
    for (int r = 0; r < 4; ++r) {
      int row = rowbase + r;
      if (row >= M_ROWS) continue;
      int b = row / SEQ;
      int s = row - b * SEQ;
#pragma unroll
      for (int j = 0; j < 4; ++j) {
        int d = j * 16 + fr;
        float v = acc[i][j][r];
        float outv;
        if (mode == 2) {
          outv = v + bv[n0 + wn + d];
        } else {
          float vb = v;
          int jp = j ^ 2;
          float pv = acc[i][jp][r];
          if (mode == 0) {
            vb += bq[n0 + wn + d];
            pv += bq[n0 + wn + (jp * 16 + fr)];
          }
          if (s >= NPREF) {
            int p = s - NPREF;
            float c = rc[p * HD + d];
            float sn = rs[p * HD + d];
            float rot = (d < 32) ? -pv : pv;
            outv = vb * c + rot * sn;
          } else {
            outv = vb;
          }
          if (mode == 0) outv *= 0.125f;
        }
        dst[((size_t)(b * NH + h) * SEQ + s) * HD + d] = f2bf(outv);
      }
    }
  }
}

// ---------------- flash attention, S^T layout, reg-prefetch K/V ----------------
__global__ __launch_bounds__(256) void k_attn(
    const u16* __restrict__ Qg, const u16* __restrict__ Kg, const u16* __restrict__ Vg,
    u16* __restrict__ AO)
{
  int bh = blockIdx.x;
  int q0 = blockIdx.y * 128;
  int b = bh >> 4, h = bh & 15;
  const size_t base = (size_t)bh * SEQ * HD;

  __shared__ u16 Ks[64 * 72];
  __shared__ u16 Vt[64 * 72];
  __shared__ u16 Ps[4][32 * 72];

  int t = threadIdx.x, lane = t & 63, wv = t >> 6;
  int fr = lane & 15, quad = lane >> 4;

  int ki = t >> 2;
  int kc0 = (t & 3) * 16;
  int vs0 = (t & 31) * 2;
  int vdo = (t >> 5) * 8;

  bf16x8 qf[2][2];
#pragma unroll
  for (int qt = 0; qt < 2; ++qt) {
#pragma unroll
    for (int st = 0; st < 2; ++st) {
      int row = q0 + wv * 32 + qt * 16 + fr;
      if (row >= SEQ) row = SEQ - 1;
      qf[qt][st] = *reinterpret_cast<const bf16x8*>(Qg + base + (size_t)row * HD + st * 32 + quad * 8);
    }
  }

  u16x8 one16 = {0x3F80, 0x3F80, 0x3F80, 0x3F80, 0x3F80, 0x3F80, 0x3F80, 0x3F80};
  bf16x8 vone = __builtin_bit_cast(bf16x8, one16);

  f32x4 zero4 = {0.f, 0.f, 0.f, 0.f};
  f32x4 o[2][5];
#pragma unroll
  for (int qt = 0; qt < 2; ++qt)
#pragma unroll
    for (int di = 0; di < 5; ++di) o[qt][di] = zero4;

  uint4 krA0, krA1, vrA0, vrA1;
  {
    int kr = ki; if (kr >= SEQ) kr = SEQ - 1;
    const u16* ksrc = Kg + base + (size_t)kr * HD;
    krA0 = *reinterpret_cast<const uint4*>(ksrc + kc0);
    krA1 = *reinterpret_cast<const uint4*>(ksrc + kc0 + 8);
    int r0 = vs0; if (r0 >= SEQ) r0 = SEQ - 1;
    int r1 = vs0 + 1; if (r1 >= SEQ) r1 = SEQ - 1;
    vrA0 = *reinterpret_cast<const uint4*>(Vg + base + (size_t)r0 * HD + vdo);
    vrA1 = *reinterpret_cast<const uint4*>(Vg + base + (size_t)r1 * HD + vdo);
  }

  for (int kt = 0; kt < 17; ++kt) {
    int k0 = kt * 64;
    BAR_LGKM;
    *reinterpret_cast<uint4*>(&Ks[ki * 72 + kc0]) = krA0;
    *reinterpret_cast<uint4*>(&Ks[ki * 72 + kc0 + 8]) = krA1;
    {
      u16 v0[8], v1[8];
      *reinterpret_cast<uint4*>(v0) = vrA0;
      *reinterpret_cast<uint4*>(v1) = vrA1;
#pragma unroll
      for (int j = 0; j < 8; ++j) {
        unsigned pk = (unsigned)v0[j] | ((unsigned)v1[j] << 16);
        *reinterpret_cast<unsigned*>(&Vt[(vdo + j) * 72 + vs0]) = pk;
      }
    }
    if (kt < 16) {
      int kn = k0 + 64;
      int kr = kn + ki; if (kr >= SEQ) kr = SEQ - 1;
      const u16* ksrc = Kg + base + (size_t)kr * HD;
      krA0 = *reinterpret_cast<const uint4*>(ksrc + kc0);
      krA1 = *reinterpret_cast<const uint4*>(ksrc + kc0 + 8);
      int r0 = kn + vs0; if (r0 >= SEQ) r0 = SEQ - 1;
      int r1 = kn + vs0 + 1; if (r1 >= SEQ) r1 = SEQ - 1;
      vrA0 = *reinterpret_cast<const uint4*>(Vg + base + (size_t)r0 * HD + vdo);
      vrA1 = *reinterpret_cast<const uint4*>(Vg + base + (size_t)r1 * HD + vdo);
    }
    BAR_LGKM;

    f32x4 sc[4][2];
#pragma unroll
    for (int mi = 0; mi < 4; ++mi)
#pragma unroll
      for (int qt = 0; qt < 2; ++qt) sc[mi][qt] = zero4;
#pragma unroll
    for (int st = 0; st < 2; ++st) {
#pragma unroll
      for (int mi = 0; mi < 4; ++mi) {
        bf16x8 kf = *reinterpret_cast<const bf16x8*>(&Ks[(mi * 16 + fr) * 72 + st * 32 + quad * 8]);
#pragma unroll
        for (int qt = 0; qt < 2; ++qt)
          sc[mi][qt] = __builtin_amdgcn_mfma_f32_16x16x32_bf16(kf, qf[qt][st], sc[mi][qt], 0, 0, 0);
      }
    }

    bool last = (kt == 16);
#pragma unroll
    for (int qt = 0; qt < 2; ++qt) {
#pragma unroll
      for (int mi = 0; mi < 4; ++mi) {
        float p0, p1, p2, p3;
        {
          float s0v = sc[mi][qt][0], s1v = sc[mi][qt][1], s2v = sc[mi][qt][2], s3v = sc[mi][qt][3];
          if (last) {
            int kc = mi * 16 + quad * 4;
            if (kc + 0 >= NPREF) s0v = -1e30f;
            if (kc + 1 >= NPREF) s1v = -1e30f;
            if (kc + 2 >= NPREF) s2v = -1e30f;
            if (kc + 3 >= NPREF) s3v = -1e30f;
          }
          p0 = __expf(s0v - 16.0f);
          p1 = __expf(s1v - 16.0f);
          p2 = __expf(s2v - 16.0f);
          p3 = __expf(s3v - 16.0f);
        }
        unsigned d0 = pk2bf(p0, p1);
        unsigned d1 = pk2bf(p2, p3);
        uint2 w; w.x = d0; w.y = d1;
        *reinterpret_cast<uint2*>(&Ps[wv][(qt * 16 + fr) * 72 + mi * 16 + quad * 4]) = w;
      }
    }

#pragma unroll
    for (int st = 0; st < 2; ++st) {
      bf16x8 pf[2];
#pragma unroll
      for (int qt = 0; qt < 2; ++qt)
        pf[qt] = *reinterpret_cast<const bf16x8*>(&Ps[wv][(qt * 16 + fr) * 72 + st * 32 + quad * 8]);
#pragma unroll
      for (int di = 0; di < 4; ++di) {
        bf16x8 vf = *reinterpret_cast<const bf16x8*>(&Vt[(di * 16 + fr) * 72 + st * 32 + quad * 8]);
#pragma unroll
        for (int qt = 0; qt < 2; ++qt)
          o[qt][di] = __builtin_amdgcn_mfma_f32_16x16x32_bf16(pf[qt], vf, o[qt][di], 0, 0, 0);
      }
#pragma unroll
      for (int qt = 0; qt < 2; ++qt)
        o[qt][4] = __builtin_amdgcn_mfma_f32_16x16x32_bf16(pf[qt], vone, o[qt][4], 0, 0, 0);
    }
  }

#pragma unroll
  for (int qt = 0; qt < 2; ++qt) {
#pragma unroll
    for (int r = 0; r < 4; ++r) {
      int srow = q0 + wv * 32 + qt * 16 + quad * 4 + r;
      if (srow >= SEQ) continue;
      float inv = 1.f / o[qt][4][r];
#pragma unroll
      for (int di = 0; di < 4; ++di) {
        float v = o[qt][di][r] * inv;
        AO[((size_t)b * SEQ + srow) * DIMN + h * HD + di * 16 + fr] = f2bf(v);
      }
    }
  }
}

// ---------------- output GEMM, LDS-free register pipeline ----------------
// grid 520 = mt(65) x nt(8, fastest)
__global__ __launch_bounds__(256) void k_out(
    const u16* __restrict__ Ab, const u16* __restrict__ WoT,
    const float* __restrict__ bo, float* __restrict__ Out)
{
  int bid = blockIdx.x;
  int nt = bid & 7;
  int mt = bid >> 3;
  int m0 = mt * 128, n0 = nt * 128;

  int t = threadIdx.x, lane = t & 63, wv = t >> 6;
  int fr = lane & 15, quad = lane >> 4;
  int wm = (wv >> 1) * 64, wn = (wv & 1) * 64;

  const u16* ap[4];
  const u16* bp[4];
#pragma unroll
  for (int i = 0; i < 4; ++i) {
    int arow = m0 + wm + i * 16 + fr; if (arow >= M_ROWS) arow = M_ROWS - 1;
    ap[i] = Ab + (size_t)arow * DIMN + quad * 8;
    int brow = n0 + wn + i * 16 + fr;
    bp[i] = WoT + (size_t)brow * DIMN + quad * 8;
  }

  f32x4 zero4 = {0.f, 0.f, 0.f, 0.f};
  f32x4 acc[4][4];
#pragma unroll
  for (int i = 0; i < 4; ++i)
#pragma unroll
    for (int j = 0; j < 4; ++j) acc[i][j] = zero4;

  bf16x8 ac[4], bc[4], an[4], bn[4];
#pragma unroll
  for (int i = 0; i < 4; ++i) {
    ac[i] = *reinterpret_cast<const bf16x8*>(ap[i]);
    bc[i] = *reinterpret_cast<const bf16x8*>(bp[i]);
  }

#pragma unroll 2
  for (int k0 = 0; k0 < DIMN; k0 += 32) {
    if (k0 < DIMN - 32) {
#pragma unroll
      for (int i = 0; i < 4; ++i) {
        an[i] = *reinterpret_cast<const bf16x8*>(ap[i] + k0 + 32);
        bn[i] = *reinterpret_cast<const bf16x8*>(bp[i] + k0 + 32);
      }
    }
#pragma unroll
    for (int i = 0; i < 4; ++i)
#pragma unroll
      for (int j = 0; j < 4; ++j)
        acc[i][j] = __builtin_amdgcn_mfma_f32_16x16x32_bf16(ac[i], bc[j], acc[i][j], 0, 0, 0);
#pragma unroll
    for (int i = 0; i < 4; ++i) { ac[i] = an[i]; bc[i] = bn[i]; }
  }

#pragma unroll
  for (int i = 0; i < 4; ++i) {
    int rowbase = m0 + wm + i * 16 + quad * 4;
#pragma unroll
    for (int r = 0; r < 4; ++r) {
      int row = rowbase + r;
      if (row >= M_ROWS) continue;
#pragma unroll
      for (int j = 0; j < 4; ++j) {
        int col = n0 + wn + j * 16 + fr;
        Out[(size_t)row * DIMN + col] = acc[i][j][r] + bo[col];
      }
    }
  }
}

extern "C" void kernel_launch(void* const* d_in, const int* in_sizes, int n_in,
                              void* d_out, int out_size, void* d_ws, size_t ws_size,
                              hipStream_t stream)
{
  const float* x  = (const float*)d_in[0];
  const float* rc = (const float*)d_in[1];
  const float* rs = (const float*)d_in[2];
  const float* Wq = (const float*)d_in[3];
  const float* bq = (const float*)d_in[4];
  const float* Wk = (const float*)d_in[5];
  const float* Wv = (const float*)d_in[6];
  const float* bv = (const float*)d_in[7];
  const float* Wo = (const float*)d_in[8];
  const float* bo = (const float*)d_in[9];
  float* Out = (float*)d_out;

  u16* p = (u16*)d_ws;
  u16* Xb  = p; p += (size_t)M_ROWS * DIMN;
  u16* WqT = p; p += (size_t)DIMN * DIMN;
  u16* WkT = p; p += (size_t)DIMN * DIMN;
  u16* WvT = p; p += (size_t)DIMN * DIMN;
  u16* WoT = p; p += (size_t)DIMN * DIMN;
  u16* Qg  = p; p += (size_t)M_ROWS * DIMN;
  u16* Kg  = p; p += (size_t)M_ROWS * DIMN;
  u16* Vg  = p; p += (size_t)M_ROWS * DIMN;
  u16* AO  = p; p += (size_t)M_ROWS * DIMN;

  k_cvt_x<<<M_ROWS, 256, 0, stream>>>(x, Xb);
  dim3 gt(32, 32, 4);
  k_wt<<<gt, 256, 0, stream>>>(Wq, Wk, Wv, Wo, WqT, WkT, WvT, WoT);
  k_qkv<<<1560, 256, 0, stream>>>(Xb, WqT, WkT, WvT, bq, bv, rc, rs, Qg, Kg, Vg);
  dim3 g2(128, 9);
  k_attn<<<g2, 256, 0, stream>>>(Qg, Kg, Vg, AO);
  k_out<<<520, 256, 0, stream>>>(AO, WoT, bo, Out);
}

// Round 6
// 351.232 us; speedup vs baseline: 1.4364x; 1.4364x over previous
//
#include <hip/hip_runtime.h>

typedef unsigned short u16;
typedef __bf16 bf16x8 __attribute__((ext_vector_type(8)));
typedef unsigned short u16x8 __attribute__((ext_vector_type(8)));
typedef float f32x4 __attribute__((ext_vector_type(4)));

#define M_ROWS 8232
#define SEQ 1029
#define NPREF 5
#define DIMN 1024
#define NH 16
#define HD 64

// raw barrier for attn: LDS-only wait, no vmem drain
#define BAR_LGKM asm volatile("s_waitcnt lgkmcnt(0)\ns_barrier" ::: "memory")

__device__ __forceinline__ u16 f2bf(float f) {
  unsigned u = __float_as_uint(f);
  u += 0x7fffu + ((u >> 16) & 1u);
  return (u16)(u >> 16);
}

__device__ __forceinline__ unsigned pk2bf(float lo, float hi) {
  unsigned ul = __float_as_uint(lo);
  unsigned uh = __float_as_uint(hi);
  ul += 0x7fffu + ((ul >> 16) & 1u);
  uh += 0x7fffu + ((uh >> 16) & 1u);
  return __builtin_amdgcn_perm(uh, ul, 0x07060302u);
}

// ---------------- x (fp32) -> Xpack (bf16, fragment-major lines) ----------------
// line = ((mt*2+g)*4 + i)*32 + kk ; lane l holds A[mt*128+g*64+i*16+(l&15)][kk*32+(l>>4)*8 ..+8]
// block: 64 rows x 256 cols. grid (4 col-blocks, 130 row-blocks)
__global__ __launch_bounds__(256) void k_pack_x(const float* __restrict__ x, u16* __restrict__ Xp) {
  int cb = blockIdx.x;  // 0..3
  int rb = blockIdx.y;  // 0..129
  __shared__ u16 Tl[64 * 264];
  int t = threadIdx.x;
#pragma unroll
  for (int p = 0; p < 16; ++p) {
    int idx = p * 256 + t;      // over 64 rows x 64 float4
    int row = idx >> 6;
    int c4 = idx & 63;
    int grow = rb * 64 + row; if (grow >= M_ROWS) grow = M_ROWS - 1;
    float4 v = *reinterpret_cast<const float4*>(x + (size_t)grow * DIMN + cb * 256 + c4 * 4);
    ushort4 o;
    o.x = f2bf(v.x); o.y = f2bf(v.y); o.z = f2bf(v.z); o.w = f2bf(v.w);
    *reinterpret_cast<ushort4*>(&Tl[row * 264 + c4 * 4]) = o;
  }
  __syncthreads();
  int wv = t >> 6, lane = t & 63;
  int mt = rb >> 1, g = rb & 1;
#pragma unroll
  for (int li = 0; li < 8; ++li) {
    int ll = wv * 8 + li;       // 0..31
    int i = ll >> 3;
    int kkl = ll & 7;
    int row = i * 16 + (lane & 15);
    int col = kkl * 32 + (lane >> 4) * 8;
    uint4 d = *reinterpret_cast<const uint4*>(&Tl[row * 264 + col]);
    size_t line = ((size_t)(mt * 2 + g) * 4 + i) * 32 + (cb * 8 + kkl);
    *reinterpret_cast<uint4*>(Xp + line * 512 + lane * 8) = d;
  }
}

// ---------------- W (fp32 [K][N]) -> Wpack (bf16, fragment-major lines) ----------------
// line = n16*32 + kk ; lane l holds W[kk*32+(l>>4)*8+dk][n16*16+(l&15)] (i.e. WT[n][k])
// block: 64k x 64n. grid (16 kb, 16 nb, 4 matrices)
__global__ __launch_bounds__(256) void k_wt(const float* __restrict__ W0, const float* __restrict__ W1,
                                            const float* __restrict__ W2, const float* __restrict__ W3,
                                            u16* __restrict__ P0, u16* __restrict__ P1,
                                            u16* __restrict__ P2, u16* __restrict__ P3) {
  const float* W; u16* P;
  switch (blockIdx.z) {
    case 0: W = W0; P = P0; break;
    case 1: W = W1; P = P1; break;
    case 2: W = W2; P = P2; break;
    default: W = W3; P = P3; break;
  }
  __shared__ float tile[64 * 68];
  int t = threadIdx.x;
  int kb = blockIdx.x, nb = blockIdx.y;
#pragma unroll
  for (int p = 0; p < 16; ++p) {
    int idx = p * 256 + t;
    int row = idx >> 6, col = idx & 63;
    tile[row * 68 + col] = W[(size_t)(kb * 64 + row) * DIMN + nb * 64 + col];
  }
  __syncthreads();
  int wv = t >> 6, lane = t & 63;
#pragma unroll
  for (int li = 0; li < 2; ++li) {
    int ll = wv * 2 + li;       // 0..7
    int jg = ll >> 1, kkl = ll & 1;
    int n = jg * 16 + (lane & 15);
    int kc = kkl * 32 + (lane >> 4) * 8;
    u16 buf[8];
#pragma unroll
    for (int dk = 0; dk < 8; ++dk) buf[dk] = f2bf(tile[(kc + dk) * 68 + n]);
    size_t line = (size_t)(nb * 4 + jg) * 32 + kb * 2 + kkl;
    *reinterpret_cast<uint4*>(P + line * 512 + lane * 8) = *reinterpret_cast<const uint4*>(buf);
  }
}

#define MM16(AF, BF) do { \
  _Pragma("unroll") for (int i_ = 0; i_ < 4; ++i_) \
  _Pragma("unroll") for (int j_ = 0; j_ < 4; ++j_) \
    acc[i_][j_] = __builtin_amdgcn_mfma_f32_16x16x32_bf16(AF[i_], BF[j_], acc[i_][j_], 0, 0, 0); \
} while (0)

#define LDFRAG(AA, BB, KK) do { \
  _Pragma("unroll") for (int i_ = 0; i_ < 4; ++i_) { \
    AA[i_] = *reinterpret_cast<const bf16x8*>(abase + (size_t)i_ * 16384 + (size_t)(KK) * 512); \
    BB[i_] = *reinterpret_cast<const bf16x8*>(bbase + (size_t)i_ * 16384 + (size_t)(KK) * 512); \
  } } while (0)

// ---------------- fused QKV projection GEMM: packed frags, no LDS, no barriers ----------------
// grid 1560 = mode(3, slow) x mt(65) x nt(8, fast)
__global__ __launch_bounds__(256) void k_qkv(
    const u16* __restrict__ Xp,
    const u16* __restrict__ Pq, const u16* __restrict__ Pk, const u16* __restrict__ Pv,
    const float* __restrict__ bq, const float* __restrict__ bv,
    const float* __restrict__ rc, const float* __restrict__ rs,
    u16* __restrict__ Qg, u16* __restrict__ Kg, u16* __restrict__ Vg)
{
  int bid = blockIdx.x;
  int nt = bid & 7;
  int tmp = bid >> 3;
  int mt = tmp % 65;
  int mode = tmp / 65;
  const u16* Wp = (mode == 0) ? Pq : (mode == 1) ? Pk : Pv;
  u16* dst = (mode == 0) ? Qg : (mode == 1) ? Kg : Vg;
  int m0 = mt * 128, n0 = nt * 128;

  int t = threadIdx.x, lane = t & 63, wv = t >> 6;
  int fr = lane & 15, quad = lane >> 4;
  int ga = wv >> 1, gb = wv & 1;
  int wm = ga * 64, wn = gb * 64;

  const u16* abase = Xp + ((size_t)(mt * 2 + ga) * 4 * 32) * 512 + lane * 8;
  const u16* bbase = Wp + ((size_t)(nt * 2 + gb) * 4 * 32) * 512 + lane * 8;

  f32x4 zero4 = {0.f, 0.f, 0.f, 0.f};
  f32x4 acc[4][4];
#pragma unroll
  for (int i = 0; i < 4; ++i)
#pragma unroll
    for (int j = 0; j < 4; ++j) acc[i][j] = zero4;

  bf16x8 a0[4], b0[4], a1[4], b1[4];
  LDFRAG(a0, b0, 0);
  for (int kk = 0; kk < 32; kk += 2) {
    if (kk + 1 < 32) LDFRAG(a1, b1, kk + 1);
    MM16(a0, b0);
    if (kk + 2 < 32) LDFRAG(a0, b0, kk + 2);
    MM16(a1, b1);
  }

  int h = (n0 + wn) >> 6;
#pragma unroll
  for (int i = 0; i < 4; ++i) {
    int rowbase = m0 + wm + i * 16 + quad * 4;
#pragma unroll
    for (int r = 0; r < 4; ++r) {
      int row = rowbase + r;
      if (row >= M_ROWS) continue;
      int b = row / SEQ;
      int s = row - b * SEQ;
#pragma unroll
      for (int j = 0; j < 4; ++j) {
        int d = j * 16 + fr;
        float v = acc[i][j][r];
        float outv;
        if (mode == 2) {
          outv = v + bv[n0 + wn + d];
        } else {
          float vb = v;
          int jp = j ^ 2;
          float pv = acc[i][jp][r];
          if (mode == 0) {
            vb += bq[n0 + wn + d];
            pv += bq[n0 + wn + (jp * 16 + fr)];
          }
          if (s >= NPREF) {
            int p = s - NPREF;
            float c = rc[p * HD + d];
            float sn = rs[p * HD + d];
            float rot = (d < 32) ? -pv : pv;
            outv = vb * c + rot * sn;
          } else {
            outv = vb;
          }
          if (mode == 0) outv *= 0.125f;
        }
        dst[((size_t)(b * NH + h) * SEQ + s) * HD + d] = f2bf(outv);
      }
    }
  }
}

// ---------------- flash attention; epilogue writes AO in packed-fragment layout ----------------
// grid (x=128 bh, y=9 mtb)
__global__ __launch_bounds__(256) void k_attn(
    const u16* __restrict__ Qg, const u16* __restrict__ Kg, const u16* __restrict__ Vg,
    u16* __restrict__ AOp)
{
  int bh = blockIdx.x;
  int mtb = blockIdx.y;
  int q0 = mtb * 128;
  int b = bh >> 4, h = bh & 15;
  const size_t base = (size_t)bh * SEQ * HD;

  __shared__ u16 KV[128 * 72];     // Ks = rows 0..63, Vt = rows 64..127; reused as 128x72 transpose buffer
  __shared__ u16 Ps[4][32 * 72];
  u16* Ks = KV;
  u16* Vt = KV + 64 * 72;

  int t = threadIdx.x, lane = t & 63, wv = t >> 6;
  int fr = lane & 15, quad = lane >> 4;

  int ki = t >> 2;
  int kc0 = (t & 3) * 16;
  int vs0 = (t & 31) * 2;
  int vdo = (t >> 5) * 8;

  bf16x8 qf[2][2];
#pragma unroll
  for (int qt = 0; qt < 2; ++qt) {
#pragma unroll
    for (int st = 0; st < 2; ++st) {
      int row = q0 + wv * 32 + qt * 16 + fr;
      if (row >= SEQ) row = SEQ - 1;
      qf[qt][st] = *reinterpret_cast<const bf16x8*>(Qg + base + (size_t)row * HD + st * 32 + quad * 8);
    }
  }

  u16x8 one16 = {0x3F80, 0x3F80, 0x3F80, 0x3F80, 0x3F80, 0x3F80, 0x3F80, 0x3F80};
  bf16x8 vone = __builtin_bit_cast(bf16x8, one16);

  f32x4 zero4 = {0.f, 0.f, 0.f, 0.f};
  f32x4 o[2][5];
#pragma unroll
  for (int qt = 0; qt < 2; ++qt)
#pragma unroll
    for (int di = 0; di < 5; ++di) o[qt][di] = zero4;

  uint4 krA0, krA1, vrA0, vrA1;
  {
    int kr = ki; if (kr >= SEQ) kr = SEQ - 1;
    const u16* ksrc = Kg + base + (size_t)kr * HD;
    krA0 = *reinterpret_cast<const uint4*>(ksrc + kc0);
    krA1 = *reinterpret_cast<const uint4*>(ksrc + kc0 + 8);
    int r0 = vs0; if (r0 >= SEQ) r0 = SEQ - 1;
    int r1 = vs0 + 1; if (r1 >= SEQ) r1 = SEQ - 1;
    vrA0 = *reinterpret_cast<const uint4*>(Vg + base + (size_t)r0 * HD + vdo);
    vrA1 = *reinterpret_cast<const uint4*>(Vg + base + (size_t)r1 * HD + vdo);
  }

  for (int kt = 0; kt < 17; ++kt) {
    int k0 = kt * 64;
    BAR_LGKM;
    *reinterpret_cast<uint4*>(&Ks[ki * 72 + kc0]) = krA0;
    *reinterpret_cast<uint4*>(&Ks[ki * 72 + kc0 + 8]) = krA1;
    {
      u16 v0[8], v1[8];
      *reinterpret_cast<uint4*>(v0) = vrA0;
      *reinterpret_cast<uint4*>(v1) = vrA1;
#pragma unroll
      for (int j = 0; j < 8; ++j) {
        unsigned pk = (unsigned)v0[j] | ((unsigned)v1[j] << 16);
        *reinterpret_cast<unsigned*>(&Vt[(vdo + j) * 72 + vs0]) = pk;
      }
    }
    if (kt < 16) {
      int kn = k0 + 64;
      int kr = kn + ki; if (kr >= SEQ) kr = SEQ - 1;
      const u16* ksrc = Kg + base + (size_t)kr * HD;
      krA0 = *reinterpret_cast<const uint4*>(ksrc + kc0);
      krA1 = *reinterpret_cast<const uint4*>(ksrc + kc0 + 8);
      int r0 = kn + vs0; if (r0 >= SEQ) r0 = SEQ - 1;
      int r1 = kn + vs0 + 1; if (r1 >= SEQ) r1 = SEQ - 1;
      vrA0 = *reinterpret_cast<const uint4*>(Vg + base + (size_t)r0 * HD + vdo);
      vrA1 = *reinterpret_cast<const uint4*>(Vg + base + (size_t)r1 * HD + vdo);
    }
    BAR_LGKM;

    f32x4 sc[4][2];
#pragma unroll
    for (int mi = 0; mi < 4; ++mi)
#pragma unroll
      for (int qt = 0; qt < 2; ++qt) sc[mi][qt] = zero4;
#pragma unroll
    for (int st = 0; st < 2; ++st) {
#pragma unroll
      for (int mi = 0; mi < 4; ++mi) {
        bf16x8 kf = *reinterpret_cast<const bf16x8*>(&Ks[(mi * 16 + fr) * 72 + st * 32 + quad * 8]);
#pragma unroll
        for (int qt = 0; qt < 2; ++qt)
          sc[mi][qt] = __builtin_amdgcn_mfma_f32_16x16x32_bf16(kf, qf[qt][st], sc[mi][qt], 0, 0, 0);
      }
    }

    bool last = (kt == 16);
#pragma unroll
    for (int qt = 0; qt < 2; ++qt) {
#pragma unroll
      for (int mi = 0; mi < 4; ++mi) {
        float p0, p1, p2, p3;
        {
          float s0v = sc[mi][qt][0], s1v = sc[mi][qt][1], s2v = sc[mi][qt][2], s3v = sc[mi][qt][3];
          if (last) {
            int kc = mi * 16 + quad * 4;
            if (kc + 0 >= NPREF) s0v = -1e30f;
            if (kc + 1 >= NPREF) s1v = -1e30f;
            if (kc + 2 >= NPREF) s2v = -1e30f;
            if (kc + 3 >= NPREF) s3v = -1e30f;
          }
          p0 = __expf(s0v - 16.0f);
          p1 = __expf(s1v - 16.0f);
          p2 = __expf(s2v - 16.0f);
          p3 = __expf(s3v - 16.0f);
        }
        unsigned d0 = pk2bf(p0, p1);
        unsigned d1 = pk2bf(p2, p3);
        uint2 w; w.x = d0; w.y = d1;
        *reinterpret_cast<uint2*>(&Ps[wv][(qt * 16 + fr) * 72 + mi * 16 + quad * 4]) = w;
      }
    }

#pragma unroll
    for (int st = 0; st < 2; ++st) {
      bf16x8 pf[2];
#pragma unroll
      for (int qt = 0; qt < 2; ++qt)
        pf[qt] = *reinterpret_cast<const bf16x8*>(&Ps[wv][(qt * 16 + fr) * 72 + st * 32 + quad * 8]);
#pragma unroll
      for (int di = 0; di < 4; ++di) {
        bf16x8 vf = *reinterpret_cast<const bf16x8*>(&Vt[(di * 16 + fr) * 72 + st * 32 + quad * 8]);
#pragma unroll
        for (int qt = 0; qt < 2; ++qt)
          o[qt][di] = __builtin_amdgcn_mfma_f32_16x16x32_bf16(pf[qt], vf, o[qt][di], 0, 0, 0);
      }
#pragma unroll
      for (int qt = 0; qt < 2; ++qt)
        o[qt][4] = __builtin_amdgcn_mfma_f32_16x16x32_bf16(pf[qt], vone, o[qt][4], 0, 0, 0);
    }
  }

  // epilogue: normalize -> LDS transpose (reuse KV as 128x72) -> packed-fragment AO lines
  __syncthreads();
#pragma unroll
  for (int qt = 0; qt < 2; ++qt) {
#pragma unroll
    for (int r = 0; r < 4; ++r) {
      int rowl = wv * 32 + qt * 16 + quad * 4 + r;
      bool valid = (q0 + rowl) < SEQ;
      float inv = valid ? (1.f / o[qt][4][r]) : 0.f;
#pragma unroll
      for (int di = 0; di < 4; ++di)
        KV[rowl * 72 + di * 16 + fr] = f2bf(o[qt][di][r] * inv);
    }
  }
  __syncthreads();
#pragma unroll
  for (int li = 0; li < 4; ++li) {
    int ll = wv * 4 + li;        // 0..15
    int g = ll >> 3, i = (ll >> 1) & 3, kkl = ll & 1;
    int rowl = g * 64 + i * 16 + (lane & 15);
    int col = kkl * 32 + (lane >> 4) * 8;
    uint4 d = *reinterpret_cast<const uint4*>(&KV[rowl * 72 + col]);
    size_t line = ((size_t)((b * 9 + mtb) * 2 + g) * 4 + i) * 32 + (h * 2 + kkl);
    *reinterpret_cast<uint4*>(AOp + line * 512 + lane * 8) = d;
  }
}

// ---------------- output GEMM: packed frags, no LDS, no barriers ----------------
// grid 576 = b(8) x mtb(9) x nt(8, fast)
__global__ __launch_bounds__(256) void k_out(
    const u16* __restrict__ AOp, const u16* __restrict__ Po,
    const float* __restrict__ bo, float* __restrict__ Out)
{
  int bid = blockIdx.x;
  int nt = bid & 7;
  int tmp = bid >> 3;
  int mtb = tmp % 9;
  int b = tmp / 9;
  int n0 = nt * 128;

  int t = threadIdx.x, lane = t & 63, wv = t >> 6;
  int fr = lane & 15, quad = lane >> 4;
  int ga = wv >> 1, gb = wv & 1;
  int wm = ga * 64, wn = gb * 64;

  const u16* abase = AOp + ((size_t)((b * 9 + mtb) * 2 + ga) * 4 * 32) * 512 + lane * 8;
  const u16* bbase = Po + ((size_t)(nt * 2 + gb) * 4 * 32) * 512 + lane * 8;

  f32x4 zero4 = {0.f, 0.f, 0.f, 0.f};
  f32x4 acc[4][4];
#pragma unroll
  for (int i = 0; i < 4; ++i)
#pragma unroll
    for (int j = 0; j < 4; ++j) acc[i][j] = zero4;

  bf16x8 a0[4], b0[4], a1[4], b1[4];
  LDFRAG(a0, b0, 0);
  for (int kk = 0; kk < 32; kk += 2) {
    if (kk + 1 < 32) LDFRAG(a1, b1, kk + 1);
    MM16(a0, b0);
    if (kk + 2 < 32) LDFRAG(a0, b0, kk + 2);
    MM16(a1, b1);
  }

#pragma unroll
  for (int i = 0; i < 4; ++i) {
    int rowbase = mtb * 128 + wm + i * 16 + quad * 4;
#pragma unroll
    for (int r = 0; r < 4; ++r) {
      int rowl = rowbase + r;
      if (rowl >= SEQ) continue;
      size_t row = (size_t)b * SEQ + rowl;
#pragma unroll
      for (int j = 0; j < 4; ++j) {
        int col = n0 + wn + j * 16 + fr;
        Out[row * DIMN + col] = acc[i][j][r] + bo[col];
      }
    }
  }
}

extern "C" void kernel_launch(void* const* d_in, const int* in_sizes, int n_in,
                              void* d_out, int out_size, void* d_ws, size_t ws_size,
                              hipStream_t stream)
{
  const float* x  = (const float*)d_in[0];
  const float* rc = (const float*)d_in[1];
  const float* rs = (const float*)d_in[2];
  const float* Wq = (const float*)d_in[3];
  const float* bq = (const float*)d_in[4];
  const float* Wk = (const float*)d_in[5];
  const float* Wv = (const float*)d_in[6];
  const float* bv = (const float*)d_in[7];
  const float* Wo = (const float*)d_in[8];
  const float* bo = (const float*)d_in[9];
  float* Out = (float*)d_out;

  u16* p = (u16*)d_ws;
  u16* Xp = p; p += (size_t)16640 * 512;        // 65*2*4*32 lines
  u16* Pq = p; p += (size_t)2048 * 512;
  u16* Pk = p; p += (size_t)2048 * 512;
  u16* Pv = p; p += (size_t)2048 * 512;
  u16* Po = p; p += (size_t)2048 * 512;
  u16* Qg = p; p += (size_t)M_ROWS * DIMN;
  u16* Kg = p; p += (size_t)M_ROWS * DIMN;
  u16* Vg = p; p += (size_t)M_ROWS * DIMN;
  // AOp (18432 lines) aliases Xp+Pq (dead after k_qkv): 18432*512 <= (16640+2048)*512
  u16* AOp = Xp;

  dim3 gx(4, 130);
  k_pack_x<<<gx, 256, 0, stream>>>(x, Xp);
  dim3 gt(16, 16, 4);
  k_wt<<<gt, 256, 0, stream>>>(Wq, Wk, Wv, Wo, Pq, Pk, Pv, Po);
  k_qkv<<<1560, 256, 0, stream>>>(Xp, Pq, Pk, Pv, bq, bv, rc, rs, Qg, Kg, Vg);
  dim3 g2(128, 9);
  k_attn<<<g2, 256, 0, stream>>>(Qg, Kg, Vg, AOp);
  k_out<<<576, 256, 0, stream>>>(AOp, Po, bo, Out);
}

// Round 7
// 335.889 us; speedup vs baseline: 1.5020x; 1.0457x over previous
//
#include <hip/hip_runtime.h>

typedef unsigned short u16;
typedef __bf16 bf16x8 __attribute__((ext_vector_type(8)));
typedef unsigned short u16x8 __attribute__((ext_vector_type(8)));
typedef float f32x4 __attribute__((ext_vector_type(4)));

#define M_ROWS 8232
#define SEQ 1029
#define NPREF 5
#define DIMN 1024
#define NH 16
#define HD 64

// raw barrier for attn: LDS-only wait, no vmem drain
#define BAR_LGKM asm volatile("s_waitcnt lgkmcnt(0)\ns_barrier" ::: "memory")

__device__ __forceinline__ u16 f2bf(float f) {
  unsigned u = __float_as_uint(f);
  u += 0x7fffu + ((u >> 16) & 1u);
  return (u16)(u >> 16);
}

__device__ __forceinline__ unsigned pk2bf(float lo, float hi) {
  unsigned ul = __float_as_uint(lo);
  unsigned uh = __float_as_uint(hi);
  ul += 0x7fffu + ((ul >> 16) & 1u);
  uh += 0x7fffu + ((uh >> 16) & 1u);
  return __builtin_amdgcn_perm(uh, ul, 0x07060302u);
}

// ---------------- x (fp32) -> Xpack (bf16, fragment-major lines) ----------------
__global__ __launch_bounds__(256) void k_pack_x(const float* __restrict__ x, u16* __restrict__ Xp) {
  int cb = blockIdx.x;  // 0..3
  int rb = blockIdx.y;  // 0..129
  __shared__ u16 Tl[64 * 264];
  int t = threadIdx.x;
#pragma unroll
  for (int p = 0; p < 16; ++p) {
    int idx = p * 256 + t;
    int row = idx >> 6;
    int c4 = idx & 63;
    int grow = rb * 64 + row; if (grow >= M_ROWS) grow = M_ROWS - 1;
    float4 v = *reinterpret_cast<const float4*>(x + (size_t)grow * DIMN + cb * 256 + c4 * 4);
    ushort4 o;
    o.x = f2bf(v.x); o.y = f2bf(v.y); o.z = f2bf(v.z); o.w = f2bf(v.w);
    *reinterpret_cast<ushort4*>(&Tl[row * 264 + c4 * 4]) = o;
  }
  __syncthreads();
  int wv = t >> 6, lane = t & 63;
  int mt = rb >> 1, g = rb & 1;
#pragma unroll
  for (int li = 0; li < 8; ++li) {
    int ll = wv * 8 + li;
    int i = ll >> 3;
    int kkl = ll & 7;
    int row = i * 16 + (lane & 15);
    int col = kkl * 32 + (lane >> 4) * 8;
    uint4 d = *reinterpret_cast<const uint4*>(&Tl[row * 264 + col]);
    size_t line = ((size_t)(mt * 2 + g) * 4 + i) * 32 + (cb * 8 + kkl);
    *reinterpret_cast<uint4*>(Xp + line * 512 + lane * 8) = d;
  }
}

// ---------------- W (fp32 [K][N]) -> Wpack (bf16, fragment-major lines) ----------------
__global__ __launch_bounds__(256) void k_wt(const float* __restrict__ W0, const float* __restrict__ W1,
                                            const float* __restrict__ W2, const float* __restrict__ W3,
                                            u16* __restrict__ P0, u16* __restrict__ P1,
                                            u16* __restrict__ P2, u16* __restrict__ P3) {
  const float* W; u16* P;
  switch (blockIdx.z) {
    case 0: W = W0; P = P0; break;
    case 1: W = W1; P = P1; break;
    case 2: W = W2; P = P2; break;
    default: W = W3; P = P3; break;
  }
  __shared__ float tile[64 * 68];
  int t = threadIdx.x;
  int kb = blockIdx.x, nb = blockIdx.y;
#pragma unroll
  for (int p = 0; p < 16; ++p) {
    int idx = p * 256 + t;
    int row = idx >> 6, col = idx & 63;
    tile[row * 68 + col] = W[(size_t)(kb * 64 + row) * DIMN + nb * 64 + col];
  }
  __syncthreads();
  int wv = t >> 6, lane = t & 63;
#pragma unroll
  for (int li = 0; li < 2; ++li) {
    int ll = wv * 2 + li;
    int jg = ll >> 1, kkl = ll & 1;
    int n = jg * 16 + (lane & 15);
    int kc = kkl * 32 + (lane >> 4) * 8;
    u16 buf[8];
#pragma unroll
    for (int dk = 0; dk < 8; ++dk) buf[dk] = f2bf(tile[(kc + dk) * 68 + n]);
    size_t line = (size_t)(nb * 4 + jg) * 32 + kb * 2 + kkl;
    *reinterpret_cast<uint4*>(P + line * 512 + lane * 8) = *reinterpret_cast<const uint4*>(buf);
  }
}

#define MM16(AF, BF) do { \
  _Pragma("unroll") for (int i_ = 0; i_ < 4; ++i_) \
  _Pragma("unroll") for (int j_ = 0; j_ < 4; ++j_) \
    acc[i_][j_] = __builtin_amdgcn_mfma_f32_16x16x32_bf16(AF[i_], BF[j_], acc[i_][j_], 0, 0, 0); \
} while (0)

#define LDFRAG(AA, BB, KK) do { \
  _Pragma("unroll") for (int i_ = 0; i_ < 4; ++i_) { \
    AA[i_] = *reinterpret_cast<const bf16x8*>(abase + (size_t)i_ * 16384 + (size_t)(KK) * 512); \
    BB[i_] = *reinterpret_cast<const bf16x8*>(bbase + (size_t)i_ * 16384 + (size_t)(KK) * 512); \
  } } while (0)

// ---------------- fused QKV projection GEMM: packed frags, XCD-locked mapping ----------------
// grid 1728: xcd=bid&7; within XCD: nt fastest (A-tile sharers), then mtq (A stream),
// then mode slowest (2MB weight pack L2-resident per phase). mt = mtq*8+xcd.
__global__ __launch_bounds__(256) void k_qkv(
    const u16* __restrict__ Xp,
    const u16* __restrict__ Pq, const u16* __restrict__ Pk, const u16* __restrict__ Pv,
    const float* __restrict__ bq, const float* __restrict__ bv,
    const float* __restrict__ rc, const float* __restrict__ rs,
    u16* __restrict__ Qg, u16* __restrict__ Kg, u16* __restrict__ Vg)
{
  int bid = blockIdx.x;
  int xcd = bid & 7;
  int s = bid >> 3;           // 0..215
  int nt = s & 7;
  int s2 = s >> 3;            // 0..26
  int mode = s2 / 9;
  int mtq = s2 - mode * 9;
  int mt = mtq * 8 + xcd;
  if (mt >= 65) return;
  const u16* Wp = (mode == 0) ? Pq : (mode == 1) ? Pk : Pv;
  u16* dst = (mode == 0) ? Qg : (mode == 1) ? Kg : Vg;
  int m0 = mt * 128, n0 = nt * 128;

  int t = threadIdx.x, lane = t & 63, wv = t >> 6;
  int fr = lane & 15, quad = lane >> 4;
  int ga = wv >> 1, gb = wv & 1;
  int wm = ga * 64, wn = gb * 64;

  const u16* abase = Xp + ((size_t)(mt * 2 + ga) * 4 * 32) * 512 + lane * 8;
  const u16* bbase = Wp + ((size_t)(nt * 2 + gb) * 4 * 32) * 512 + lane * 8;

  f32x4 zero4 = {0.f, 0.f, 0.f, 0.f};
  f32x4 acc[4][4];
#pragma unroll
  for (int i = 0; i < 4; ++i)
#pragma unroll
    for (int j = 0; j < 4; ++j) acc[i][j] = zero4;

  bf16x8 a0[4], b0[4], a1[4], b1[4];
  LDFRAG(a0, b0, 0);
  for (int kk = 0; kk < 32; kk += 2) {
    if (kk + 1 < 32) LDFRAG(a1, b1, kk + 1);
    MM16(a0, b0);
    if (kk + 2 < 32) LDFRAG(a0, b0, kk + 2);
    MM16(a1, b1);
  }

  int h = (n0 + wn) >> 6;
#pragma unroll
  for (int i = 0; i < 4; ++i) {
    int rowbase = m0 + wm + i * 16 + quad * 4;
#pragma unroll
    for (int r = 0; r < 4; ++r) {
      int row = rowbase + r;
      if (row >= M_ROWS) continue;
      int b = row / SEQ;
      int sI = row - b * SEQ;
#pragma unroll
      for (int j = 0; j < 4; ++j) {
        int d = j * 16 + fr;
        float v = acc[i][j][r];
        float outv;
        if (mode == 2) {
          outv = v + bv[n0 + wn + d];
        } else {
          float vb = v;
          int jp = j ^ 2;
          float pv = acc[i][jp][r];
          if (mode == 0) {
            vb += bq[n0 + wn + d];
            pv += bq[n0 + wn + (jp * 16 + fr)];
          }
          if (sI >= NPREF) {
            int p = sI - NPREF;
            float c = rc[p * HD + d];
            float sn = rs[p * HD + d];
            float rot = (d < 32) ? -pv : pv;
            outv = vb * c + rot * sn;
          } else {
            outv = vb;
          }
          if (mode == 0) outv *= 0.125f;
        }
        dst[((size_t)(b * NH + h) * SEQ + sI) * HD + d] = f2bf(outv);
      }
    }
  }
}

// ---------------- flash attention; epilogue writes AO in packed-fragment layout ----------------
__global__ __launch_bounds__(256) void k_attn(
    const u16* __restrict__ Qg, const u16* __restrict__ Kg, const u16* __restrict__ Vg,
    u16* __restrict__ AOp)
{
  int bh = blockIdx.x;
  int mtb = blockIdx.y;
  int q0 = mtb * 128;
  int b = bh >> 4, h = bh & 15;
  const size_t base = (size_t)bh * SEQ * HD;

  __shared__ u16 KV[128 * 72];
  __shared__ u16 Ps[4][32 * 72];
  u16* Ks = KV;
  u16* Vt = KV + 64 * 72;

  int t = threadIdx.x, lane = t & 63, wv = t >> 6;
  int fr = lane & 15, quad = lane >> 4;

  int ki = t >> 2;
  int kc0 = (t & 3) * 16;
  int vs0 = (t & 31) * 2;
  int vdo = (t >> 5) * 8;

  bf16x8 qf[2][2];
#pragma unroll
  for (int qt = 0; qt < 2; ++qt) {
#pragma unroll
    for (int st = 0; st < 2; ++st) {
      int row = q0 + wv * 32 + qt * 16 + fr;
      if (row >= SEQ) row = SEQ - 1;
      qf[qt][st] = *reinterpret_cast<const bf16x8*>(Qg + base + (size_t)row * HD + st * 32 + quad * 8);
    }
  }

  u16x8 one16 = {0x3F80, 0x3F80, 0x3F80, 0x3F80, 0x3F80, 0x3F80, 0x3F80, 0x3F80};
  bf16x8 vone = __builtin_bit_cast(bf16x8, one16);

  f32x4 zero4 = {0.f, 0.f, 0.f, 0.f};
  f32x4 o[2][5];
#pragma unroll
  for (int qt = 0; qt < 2; ++qt)
#pragma unroll
    for (int di = 0; di < 5; ++di) o[qt][di] = zero4;

  uint4 krA0, krA1, vrA0, vrA1;
  {
    int kr = ki; if (kr >= SEQ) kr = SEQ - 1;
    const u16* ksrc = Kg + base + (size_t)kr * HD;
    krA0 = *reinterpret_cast<const uint4*>(ksrc + kc0);
    krA1 = *reinterpret_cast<const uint4*>(ksrc + kc0 + 8);
    int r0 = vs0; if (r0 >= SEQ) r0 = SEQ - 1;
    int r1 = vs0 + 1; if (r1 >= SEQ) r1 = SEQ - 1;
    vrA0 = *reinterpret_cast<const uint4*>(Vg + base + (size_t)r0 * HD + vdo);
    vrA1 = *reinterpret_cast<const uint4*>(Vg + base + (size_t)r1 * HD + vdo);
  }

  for (int kt = 0; kt < 17; ++kt) {
    int k0 = kt * 64;
    BAR_LGKM;
    *reinterpret_cast<uint4*>(&Ks[ki * 72 + kc0]) = krA0;
    *reinterpret_cast<uint4*>(&Ks[ki * 72 + kc0 + 8]) = krA1;
    {
      u16 v0[8], v1[8];
      *reinterpret_cast<uint4*>(v0) = vrA0;
      *reinterpret_cast<uint4*>(v1) = vrA1;
#pragma unroll
      for (int j = 0; j < 8; ++j) {
        unsigned pk = (unsigned)v0[j] | ((unsigned)v1[j] << 16);
        *reinterpret_cast<unsigned*>(&Vt[(vdo + j) * 72 + vs0]) = pk;
      }
    }
    if (kt < 16) {
      int kn = k0 + 64;
      int kr = kn + ki; if (kr >= SEQ) kr = SEQ - 1;
      const u16* ksrc = Kg + base + (size_t)kr * HD;
      krA0 = *reinterpret_cast<const uint4*>(ksrc + kc0);
      krA1 = *reinterpret_cast<const uint4*>(ksrc + kc0 + 8);
      int r0 = kn + vs0; if (r0 >= SEQ) r0 = SEQ - 1;
      int r1 = kn + vs0 + 1; if (r1 >= SEQ) r1 = SEQ - 1;
      vrA0 = *reinterpret_cast<const uint4*>(Vg + base + (size_t)r0 * HD + vdo);
      vrA1 = *reinterpret_cast<const uint4*>(Vg + base + (size_t)r1 * HD + vdo);
    }
    BAR_LGKM;

    f32x4 sc[4][2];
#pragma unroll
    for (int mi = 0; mi < 4; ++mi)
#pragma unroll
      for (int qt = 0; qt < 2; ++qt) sc[mi][qt] = zero4;
#pragma unroll
    for (int st = 0; st < 2; ++st) {
#pragma unroll
      for (int mi = 0; mi < 4; ++mi) {
        bf16x8 kf = *reinterpret_cast<const bf16x8*>(&Ks[(mi * 16 + fr) * 72 + st * 32 + quad * 8]);
#pragma unroll
        for (int qt = 0; qt < 2; ++qt)
          sc[mi][qt] = __builtin_amdgcn_mfma_f32_16x16x32_bf16(kf, qf[qt][st], sc[mi][qt], 0, 0, 0);
      }
    }

    bool last = (kt == 16);
#pragma unroll
    for (int qt = 0; qt < 2; ++qt) {
#pragma unroll
      for (int mi = 0; mi < 4; ++mi) {
        float p0, p1, p2, p3;
        {
          float s0v = sc[mi][qt][0], s1v = sc[mi][qt][1], s2v = sc[mi][qt][2], s3v = sc[mi][qt][3];
          if (last) {
            int kc = mi * 16 + quad * 4;
            if (kc + 0 >= NPREF) s0v = -1e30f;
            if (kc + 1 >= NPREF) s1v = -1e30f;
            if (kc + 2 >= NPREF) s2v = -1e30f;
            if (kc + 3 >= NPREF) s3v = -1e30f;
          }
          p0 = __expf(s0v - 16.0f);
          p1 = __expf(s1v - 16.0f);
          p2 = __expf(s2v - 16.0f);
          p3 = __expf(s3v - 16.0f);
        }
        unsigned d0 = pk2bf(p0, p1);
        unsigned d1 = pk2bf(p2, p3);
        uint2 w; w.x = d0; w.y = d1;
        *reinterpret_cast<uint2*>(&Ps[wv][(qt * 16 + fr) * 72 + mi * 16 + quad * 4]) = w;
      }
    }

#pragma unroll
    for (int st = 0; st < 2; ++st) {
      bf16x8 pf[2];
#pragma unroll
      for (int qt = 0; qt < 2; ++qt)
        pf[qt] = *reinterpret_cast<const bf16x8*>(&Ps[wv][(qt * 16 + fr) * 72 + st * 32 + quad * 8]);
#pragma unroll
      for (int di = 0; di < 4; ++di) {
        bf16x8 vf = *reinterpret_cast<const bf16x8*>(&Vt[(di * 16 + fr) * 72 + st * 32 + quad * 8]);
#pragma unroll
        for (int qt = 0; qt < 2; ++qt)
          o[qt][di] = __builtin_amdgcn_mfma_f32_16x16x32_bf16(pf[qt], vf, o[qt][di], 0, 0, 0);
      }
#pragma unroll
      for (int qt = 0; qt < 2; ++qt)
        o[qt][4] = __builtin_amdgcn_mfma_f32_16x16x32_bf16(pf[qt], vone, o[qt][4], 0, 0, 0);
    }
  }

  __syncthreads();
#pragma unroll
  for (int qt = 0; qt < 2; ++qt) {
#pragma unroll
    for (int r = 0; r < 4; ++r) {
      int rowl = wv * 32 + qt * 16 + quad * 4 + r;
      bool valid = (q0 + rowl) < SEQ;
      float inv = valid ? (1.f / o[qt][4][r]) : 0.f;
#pragma unroll
      for (int di = 0; di < 4; ++di)
        KV[rowl * 72 + di * 16 + fr] = f2bf(o[qt][di][r] * inv);
    }
  }
  __syncthreads();
#pragma unroll
  for (int li = 0; li < 4; ++li) {
    int ll = wv * 4 + li;
    int g = ll >> 3, i = (ll >> 1) & 3, kkl = ll & 1;
    int rowl = g * 64 + i * 16 + (lane & 15);
    int col = kkl * 32 + (lane >> 4) * 8;
    uint4 d = *reinterpret_cast<const uint4*>(&KV[rowl * 72 + col]);
    size_t line = ((size_t)((b * 9 + mtb) * 2 + g) * 4 + i) * 32 + (h * 2 + kkl);
    *reinterpret_cast<uint4*>(AOp + line * 512 + lane * 8) = d;
  }
}

// ---------------- output GEMM: packed frags, XCD-locked mapping ----------------
// grid 576: xcd=bid&7; s=bid>>3: nt fastest, mtq next; mid = mtq*8+xcd (exactly 72).
__global__ __launch_bounds__(256) void k_out(
    const u16* __restrict__ AOp, const u16* __restrict__ Po,
    const float* __restrict__ bo, float* __restrict__ Out)
{
  int bid = blockIdx.x;
  int xcd = bid & 7;
  int s = bid >> 3;           // 0..71
  int nt = s & 7;
  int mtq = s >> 3;           // 0..8
  int mid = mtq * 8 + xcd;    // 0..71
  int b = mid / 9, mtb = mid - b * 9;
  int n0 = nt * 128;

  int t = threadIdx.x, lane = t & 63, wv = t >> 6;
  int fr = lane & 15, quad = lane >> 4;
  int ga = wv >> 1, gb = wv & 1;
  int wm = ga * 64, wn = gb * 64;

  const u16* abase = AOp + ((size_t)(mid * 2 + ga) * 4 * 32) * 512 + lane * 8;
  const u16* bbase = Po + ((size_t)(nt * 2 + gb) * 4 * 32) * 512 + lane * 8;

  f32x4 zero4 = {0.f, 0.f, 0.f, 0.f};
  f32x4 acc[4][4];
#pragma unroll
  for (int i = 0; i < 4; ++i)
#pragma unroll
    for (int j = 0; j < 4; ++j) acc[i][j] = zero4;

  bf16x8 a0[4], b0[4], a1[4], b1[4];
  LDFRAG(a0, b0, 0);
  for (int kk = 0; kk < 32; kk += 2) {
    if (kk + 1 < 32) LDFRAG(a1, b1, kk + 1);
    MM16(a0, b0);
    if (kk + 2 < 32) LDFRAG(a0, b0, kk + 2);
    MM16(a1, b1);
  }

#pragma unroll
  for (int i = 0; i < 4; ++i) {
    int rowbase = mtb * 128 + wm + i * 16 + quad * 4;
#pragma unroll
    for (int r = 0; r < 4; ++r) {
      int rowl = rowbase + r;
      if (rowl >= SEQ) continue;
      size_t row = (size_t)b * SEQ + rowl;
#pragma unroll
      for (int j = 0; j < 4; ++j) {
        int col = n0 + wn + j * 16 + fr;
        Out[row * DIMN + col] = acc[i][j][r] + bo[col];
      }
    }
  }
}

extern "C" void kernel_launch(void* const* d_in, const int* in_sizes, int n_in,
                              void* d_out, int out_size, void* d_ws, size_t ws_size,
                              hipStream_t stream)
{
  const float* x  = (const float*)d_in[0];
  const float* rc = (const float*)d_in[1];
  const float* rs = (const float*)d_in[2];
  const float* Wq = (const float*)d_in[3];
  const float* bq = (const float*)d_in[4];
  const float* Wk = (const float*)d_in[5];
  const float* Wv = (const float*)d_in[6];
  const float* bv = (const float*)d_in[7];
  const float* Wo = (const float*)d_in[8];
  const float* bo = (const float*)d_in[9];
  float* Out = (float*)d_out;

  u16* p = (u16*)d_ws;
  u16* Xp = p; p += (size_t)16640 * 512;
  u16* Pq = p; p += (size_t)2048 * 512;
  u16* Pk = p; p += (size_t)2048 * 512;
  u16* Pv = p; p += (size_t)2048 * 512;
  u16* Po = p; p += (size_t)2048 * 512;
  u16* Qg = p; p += (size_t)M_ROWS * DIMN;
  u16* Kg = p; p += (size_t)M_ROWS * DIMN;
  u16* Vg = p; p += (size_t)M_ROWS * DIMN;
  u16* AOp = Xp;  // aliases dead Xp+Pq after k_qkv

  dim3 gx(4, 130);
  k_pack_x<<<gx, 256, 0, stream>>>(x, Xp);
  dim3 gt(16, 16, 4);
  k_wt<<<gt, 256, 0, stream>>>(Wq, Wk, Wv, Wo, Pq, Pk, Pv, Po);
  k_qkv<<<1728, 256, 0, stream>>>(Xp, Pq, Pk, Pv, bq, bv, rc, rs, Qg, Kg, Vg);
  dim3 g2(128, 9);
  k_attn<<<g2, 256, 0, stream>>>(Qg, Kg, Vg, AOp);
  k_out<<<576, 256, 0, stream>>>(AOp, Po, bo, Out);
}